// Round 11
// baseline (76.667 us; speedup 1.0000x reference)
//
#include <hip/hip_runtime.h>
#include <hip/hip_bf16.h>

// LedDetector: X [B=16, C=3, H=1080, W=1920] fp32, colors [K=3, 3] fp32.
// For each (b,k): argmin over pixels of sum_c |X[b,c,h,w] - colors[k,c]|,
// output (y, x) as floats -> d_out [B, K, 2].
//
// Streaming argmin; u64 key (dist_bits<<32)|idx, min-reduce.
// R3: 75.5us grid-stride. R8: 69.5us (chunk + x2 unroll + nt, scan ~6.05 TB/s).
// R9: 69.9us (1024 blocks / x4 unroll — stream count NOT the limiter).
// R11 (= R10 resubmit after infra failure): exact R8 kernel with nt loads
// REMOVED (plain loads) to isolate whether the no-allocate hint costs read BW.

#define LD_B    16
#define LD_W    1920
#define LD_K    3
#define LD_HW   (1080 * 1920)     // 2073600
#define LD_N4   (LD_HW / 4)       // 518400
#define LD_GX   128               // blocks per batch; 2048 total = 8/CU exactly
#define LD_CHUNK (LD_N4 / LD_GX)  // 4050 float4 per block per channel (exact)

typedef unsigned long long u64;
typedef unsigned int u32;
typedef float f4 __attribute__((ext_vector_type(4)));

__device__ __forceinline__ void led_px(float e0, float e1, float e2, u32 idx,
                                       float c00, float c01, float c02,
                                       float c10, float c11, float c12,
                                       float c20, float c21, float c22,
                                       float& minv0, u32& mini0,
                                       float& minv1, u32& mini1,
                                       float& minv2, u32& mini2) {
    float d0 = (fabsf(e0 - c00) + fabsf(e1 - c01)) + fabsf(e2 - c02);
    float d1 = (fabsf(e0 - c10) + fabsf(e1 - c11)) + fabsf(e2 - c12);
    float d2 = (fabsf(e0 - c20) + fabsf(e1 - c21)) + fabsf(e2 - c22);
    if (d0 < minv0) { minv0 = d0; mini0 = idx; }
    if (d1 < minv1) { minv1 = d1; mini1 = idx; }
    if (d2 < minv2) { minv2 = d2; mini2 = idx; }
}

#define LED_PX4(av, gv, rv, baseidx)                                            \
    led_px((av).x, (gv).x, (rv).x, (baseidx) + 0, c00,c01,c02,c10,c11,c12,      \
           c20,c21,c22, minv0,mini0,minv1,mini1,minv2,mini2);                   \
    led_px((av).y, (gv).y, (rv).y, (baseidx) + 1, c00,c01,c02,c10,c11,c12,      \
           c20,c21,c22, minv0,mini0,minv1,mini1,minv2,mini2);                   \
    led_px((av).z, (gv).z, (rv).z, (baseidx) + 2, c00,c01,c02,c10,c11,c12,      \
           c20,c21,c22, minv0,mini0,minv1,mini1,minv2,mini2);                   \
    led_px((av).w, (gv).w, (rv).w, (baseidx) + 3, c00,c01,c02,c10,c11,c12,      \
           c20,c21,c22, minv0,mini0,minv1,mini1,minv2,mini2)

template <bool ATOMIC>
__global__ __launch_bounds__(256) void led_scan(const float* __restrict__ X,
                                                const float* __restrict__ colors,
                                                u64* __restrict__ ws) {
    const int b = blockIdx.y;
    const f4* __restrict__ p0 = (const f4*)(X + (size_t)(b * 3 + 0) * LD_HW);
    const f4* __restrict__ p1 = (const f4*)(X + (size_t)(b * 3 + 1) * LD_HW);
    const f4* __restrict__ p2 = (const f4*)(X + (size_t)(b * 3 + 2) * LD_HW);

    const float c00 = colors[0], c01 = colors[1], c02 = colors[2];
    const float c10 = colors[3], c11 = colors[4], c12 = colors[5];
    const float c20 = colors[6], c21 = colors[7], c22 = colors[8];

    float minv0 = 1e30f, minv1 = 1e30f, minv2 = 1e30f;
    u32   mini0 = 0u,    mini1 = 0u,    mini2 = 0u;

    const int start = blockIdx.x * LD_CHUNK;
    const int end   = start + LD_CHUNK;

    int i = start + (int)threadIdx.x;
    // Unrolled x2; per-thread index order strictly increasing -> strict-<
    // keeps the first occurrence. Plain (cached) loads — nt A/B.
    for (; i + 256 < end; i += 512) {
        f4 a0 = p0[i];
        f4 g0 = p1[i];
        f4 r0 = p2[i];
        f4 a1 = p0[i + 256];
        f4 g1 = p1[i + 256];
        f4 r1 = p2[i + 256];

        u32 base0 = (u32)i * 4u;
        LED_PX4(a0, g0, r0, base0);
        u32 base1 = (u32)(i + 256) * 4u;
        LED_PX4(a1, g1, r1, base1);
    }
    if (i < end) {
        f4 a0 = p0[i];
        f4 g0 = p1[i];
        f4 r0 = p2[i];
        u32 base0 = (u32)i * 4u;
        LED_PX4(a0, g0, r0, base0);
    }

    u64 key0 = ((u64)__float_as_uint(minv0) << 32) | (u64)mini0;
    u64 key1 = ((u64)__float_as_uint(minv1) << 32) | (u64)mini1;
    u64 key2 = ((u64)__float_as_uint(minv2) << 32) | (u64)mini2;

#pragma unroll
    for (int off = 32; off > 0; off >>= 1) {
        u64 o0 = __shfl_down(key0, off);
        u64 o1 = __shfl_down(key1, off);
        u64 o2 = __shfl_down(key2, off);
        if (o0 < key0) key0 = o0;
        if (o1 < key1) key1 = o1;
        if (o2 < key2) key2 = o2;
    }

    __shared__ u64 sk[4][3];
    const int lane = threadIdx.x & 63;
    const int wid  = threadIdx.x >> 6;
    if (lane == 0) { sk[wid][0] = key0; sk[wid][1] = key1; sk[wid][2] = key2; }
    __syncthreads();
    if (threadIdx.x == 0) {
        u64 m0 = sk[0][0], m1 = sk[0][1], m2 = sk[0][2];
#pragma unroll
        for (int w = 1; w < 4; ++w) {
            if (sk[w][0] < m0) m0 = sk[w][0];
            if (sk[w][1] < m1) m1 = sk[w][1];
            if (sk[w][2] < m2) m2 = sk[w][2];
        }
        if (ATOMIC) {
            atomicMin(&ws[b * LD_K + 0], m0);
            atomicMin(&ws[b * LD_K + 1], m1);
            atomicMin(&ws[b * LD_K + 2], m2);
        } else {
            u64* slot = ws + (size_t)(b * LD_GX + blockIdx.x) * LD_K;
            slot[0] = m0; slot[1] = m1; slot[2] = m2;
        }
    }
}

// ---------------- final (store path): reduce 128 keys per (b,k) ----------------
__global__ __launch_bounds__(64) void led_final_store(const u64* __restrict__ ws,
                                                      float* __restrict__ out) {
    const int bk = blockIdx.x;          // 0..47
    const int b  = bk / LD_K;
    const int k  = bk % LD_K;
    const int lane = threadIdx.x;       // 0..63
    const u64* base = ws + (size_t)b * LD_GX * LD_K + k;
    u64 key = base[(size_t)lane * LD_K];
    u64 o   = base[(size_t)(lane + 64) * LD_K];
    if (o < key) key = o;
#pragma unroll
    for (int off = 32; off > 0; off >>= 1) {
        u64 s = __shfl_down(key, off);
        if (s < key) key = s;
    }
    if (lane == 0) {
        u32 idx = (u32)(key & 0xFFFFFFFFu);
        out[bk * 2 + 0] = (float)(idx / LD_W);
        out[bk * 2 + 1] = (float)(idx % LD_W);
    }
}

// ---------------- fallback (atomic path) ----------------
__global__ __launch_bounds__(64) void led_init(u64* __restrict__ ws) {
    int t = threadIdx.x;
    if (t < LD_B * LD_K) ws[t] = ~0ULL;
}

__global__ __launch_bounds__(64) void led_final_atomic(const u64* __restrict__ ws,
                                                       float* __restrict__ out) {
    int t = threadIdx.x;
    if (t < LD_B * LD_K) {
        u32 idx = (u32)(ws[t] & 0xFFFFFFFFu);
        out[t * 2 + 0] = (float)(idx / LD_W);
        out[t * 2 + 1] = (float)(idx % LD_W);
    }
}

extern "C" void kernel_launch(void* const* d_in, const int* in_sizes, int n_in,
                              void* d_out, int out_size, void* d_ws, size_t ws_size,
                              hipStream_t stream) {
    const float* X      = (const float*)d_in[0];
    const float* colors = (const float*)d_in[1];
    float* out          = (float*)d_out;
    u64*   ws           = (u64*)d_ws;

    dim3 grid(LD_GX, LD_B);   // 2048 blocks: 8/CU, single even scheduling round

    const size_t need = (size_t)LD_B * LD_GX * LD_K * sizeof(u64);  // 48 KB
    if (ws_size >= need) {
        led_scan<false><<<grid, 256, 0, stream>>>(X, colors, ws);
        led_final_store<<<LD_B * LD_K, 64, 0, stream>>>(ws, out);
    } else {
        led_init<<<1, 64, 0, stream>>>(ws);
        led_scan<true><<<grid, 256, 0, stream>>>(X, colors, ws);
        led_final_atomic<<<1, 64, 0, stream>>>(ws, out);
    }
}

// Round 12
// 69.327 us; speedup vs baseline: 1.1059x; 1.1059x over previous
//
#include <hip/hip_runtime.h>
#include <hip/hip_bf16.h>

// LedDetector: X [B=16, C=3, H=1080, W=1920] fp32, colors [K=3, 3] fp32.
// For each (b,k): argmin over pixels of sum_c |X[b,c,h,w] - colors[k,c]|,
// output (y, x) as floats -> d_out [B, K, 2].
//
// Streaming argmin; u64 key (dist_bits<<32)|idx, min-reduce.
// Ladder: R3 75.5us (grid-stride) -> R8 69.5us (chunk + x2 unroll + nt)
//         R9 69.9us (1024 blocks/x4: stream count not the limiter)
//         R11 76.7us (nt removed: nt is a +10% win on this read stream)
// This round: restore R8 exactly (best known). Scan ~6.05 TB/s = ~96% of the
// 6.29 TB/s measured read ceiling -> at practical roofline.

#define LD_B    16
#define LD_W    1920
#define LD_K    3
#define LD_HW   (1080 * 1920)     // 2073600
#define LD_N4   (LD_HW / 4)       // 518400
#define LD_GX   128               // blocks per batch; 2048 total = 8/CU exactly
#define LD_CHUNK (LD_N4 / LD_GX)  // 4050 float4 per block per channel (exact)

typedef unsigned long long u64;
typedef unsigned int u32;
typedef float f4 __attribute__((ext_vector_type(4)));   // nt-load needs clang vector

__device__ __forceinline__ void led_px(float e0, float e1, float e2, u32 idx,
                                       float c00, float c01, float c02,
                                       float c10, float c11, float c12,
                                       float c20, float c21, float c22,
                                       float& minv0, u32& mini0,
                                       float& minv1, u32& mini1,
                                       float& minv2, u32& mini2) {
    float d0 = (fabsf(e0 - c00) + fabsf(e1 - c01)) + fabsf(e2 - c02);
    float d1 = (fabsf(e0 - c10) + fabsf(e1 - c11)) + fabsf(e2 - c12);
    float d2 = (fabsf(e0 - c20) + fabsf(e1 - c21)) + fabsf(e2 - c22);
    if (d0 < minv0) { minv0 = d0; mini0 = idx; }
    if (d1 < minv1) { minv1 = d1; mini1 = idx; }
    if (d2 < minv2) { minv2 = d2; mini2 = idx; }
}

#define LED_PX4(av, gv, rv, baseidx)                                            \
    led_px((av).x, (gv).x, (rv).x, (baseidx) + 0, c00,c01,c02,c10,c11,c12,      \
           c20,c21,c22, minv0,mini0,minv1,mini1,minv2,mini2);                   \
    led_px((av).y, (gv).y, (rv).y, (baseidx) + 1, c00,c01,c02,c10,c11,c12,      \
           c20,c21,c22, minv0,mini0,minv1,mini1,minv2,mini2);                   \
    led_px((av).z, (gv).z, (rv).z, (baseidx) + 2, c00,c01,c02,c10,c11,c12,      \
           c20,c21,c22, minv0,mini0,minv1,mini1,minv2,mini2);                   \
    led_px((av).w, (gv).w, (rv).w, (baseidx) + 3, c00,c01,c02,c10,c11,c12,      \
           c20,c21,c22, minv0,mini0,minv1,mini1,minv2,mini2)

template <bool ATOMIC>
__global__ __launch_bounds__(256) void led_scan(const float* __restrict__ X,
                                                const float* __restrict__ colors,
                                                u64* __restrict__ ws) {
    const int b = blockIdx.y;
    const f4* __restrict__ p0 = (const f4*)(X + (size_t)(b * 3 + 0) * LD_HW);
    const f4* __restrict__ p1 = (const f4*)(X + (size_t)(b * 3 + 1) * LD_HW);
    const f4* __restrict__ p2 = (const f4*)(X + (size_t)(b * 3 + 2) * LD_HW);

    const float c00 = colors[0], c01 = colors[1], c02 = colors[2];
    const float c10 = colors[3], c11 = colors[4], c12 = colors[5];
    const float c20 = colors[6], c21 = colors[7], c22 = colors[8];

    float minv0 = 1e30f, minv1 = 1e30f, minv2 = 1e30f;
    u32   mini0 = 0u,    mini1 = 0u,    mini2 = 0u;

    const int start = blockIdx.x * LD_CHUNK;
    const int end   = start + LD_CHUNK;

    int i = start + (int)threadIdx.x;
    // Unrolled x2: indices i and i+256 both processed; per-thread index order
    // stays strictly increasing so strict-< keeps the first occurrence.
    for (; i + 256 < end; i += 512) {
        f4 a0 = __builtin_nontemporal_load(p0 + i);
        f4 g0 = __builtin_nontemporal_load(p1 + i);
        f4 r0 = __builtin_nontemporal_load(p2 + i);
        f4 a1 = __builtin_nontemporal_load(p0 + i + 256);
        f4 g1 = __builtin_nontemporal_load(p1 + i + 256);
        f4 r1 = __builtin_nontemporal_load(p2 + i + 256);

        u32 base0 = (u32)i * 4u;
        LED_PX4(a0, g0, r0, base0);
        u32 base1 = (u32)(i + 256) * 4u;
        LED_PX4(a1, g1, r1, base1);
    }
    if (i < end) {
        f4 a0 = __builtin_nontemporal_load(p0 + i);
        f4 g0 = __builtin_nontemporal_load(p1 + i);
        f4 r0 = __builtin_nontemporal_load(p2 + i);
        u32 base0 = (u32)i * 4u;
        LED_PX4(a0, g0, r0, base0);
    }

    u64 key0 = ((u64)__float_as_uint(minv0) << 32) | (u64)mini0;
    u64 key1 = ((u64)__float_as_uint(minv1) << 32) | (u64)mini1;
    u64 key2 = ((u64)__float_as_uint(minv2) << 32) | (u64)mini2;

#pragma unroll
    for (int off = 32; off > 0; off >>= 1) {
        u64 o0 = __shfl_down(key0, off);
        u64 o1 = __shfl_down(key1, off);
        u64 o2 = __shfl_down(key2, off);
        if (o0 < key0) key0 = o0;
        if (o1 < key1) key1 = o1;
        if (o2 < key2) key2 = o2;
    }

    __shared__ u64 sk[4][3];
    const int lane = threadIdx.x & 63;
    const int wid  = threadIdx.x >> 6;
    if (lane == 0) { sk[wid][0] = key0; sk[wid][1] = key1; sk[wid][2] = key2; }
    __syncthreads();
    if (threadIdx.x == 0) {
        u64 m0 = sk[0][0], m1 = sk[0][1], m2 = sk[0][2];
#pragma unroll
        for (int w = 1; w < 4; ++w) {
            if (sk[w][0] < m0) m0 = sk[w][0];
            if (sk[w][1] < m1) m1 = sk[w][1];
            if (sk[w][2] < m2) m2 = sk[w][2];
        }
        if (ATOMIC) {
            atomicMin(&ws[b * LD_K + 0], m0);
            atomicMin(&ws[b * LD_K + 1], m1);
            atomicMin(&ws[b * LD_K + 2], m2);
        } else {
            u64* slot = ws + (size_t)(b * LD_GX + blockIdx.x) * LD_K;
            slot[0] = m0; slot[1] = m1; slot[2] = m2;
        }
    }
}

// ---------------- final (store path): reduce 128 keys per (b,k) ----------------
__global__ __launch_bounds__(64) void led_final_store(const u64* __restrict__ ws,
                                                      float* __restrict__ out) {
    const int bk = blockIdx.x;          // 0..47
    const int b  = bk / LD_K;
    const int k  = bk % LD_K;
    const int lane = threadIdx.x;       // 0..63
    const u64* base = ws + (size_t)b * LD_GX * LD_K + k;
    u64 key = base[(size_t)lane * LD_K];
    u64 o   = base[(size_t)(lane + 64) * LD_K];
    if (o < key) key = o;
#pragma unroll
    for (int off = 32; off > 0; off >>= 1) {
        u64 s = __shfl_down(key, off);
        if (s < key) key = s;
    }
    if (lane == 0) {
        u32 idx = (u32)(key & 0xFFFFFFFFu);
        out[bk * 2 + 0] = (float)(idx / LD_W);
        out[bk * 2 + 1] = (float)(idx % LD_W);
    }
}

// ---------------- fallback (atomic path) ----------------
__global__ __launch_bounds__(64) void led_init(u64* __restrict__ ws) {
    int t = threadIdx.x;
    if (t < LD_B * LD_K) ws[t] = ~0ULL;
}

__global__ __launch_bounds__(64) void led_final_atomic(const u64* __restrict__ ws,
                                                       float* __restrict__ out) {
    int t = threadIdx.x;
    if (t < LD_B * LD_K) {
        u32 idx = (u32)(ws[t] & 0xFFFFFFFFu);
        out[t * 2 + 0] = (float)(idx / LD_W);
        out[t * 2 + 1] = (float)(idx % LD_W);
    }
}

extern "C" void kernel_launch(void* const* d_in, const int* in_sizes, int n_in,
                              void* d_out, int out_size, void* d_ws, size_t ws_size,
                              hipStream_t stream) {
    const float* X      = (const float*)d_in[0];
    const float* colors = (const float*)d_in[1];
    float* out          = (float*)d_out;
    u64*   ws           = (u64*)d_ws;

    dim3 grid(LD_GX, LD_B);   // 2048 blocks: 8/CU, single even scheduling round

    const size_t need = (size_t)LD_B * LD_GX * LD_K * sizeof(u64);  // 48 KB
    if (ws_size >= need) {
        led_scan<false><<<grid, 256, 0, stream>>>(X, colors, ws);
        led_final_store<<<LD_B * LD_K, 64, 0, stream>>>(ws, out);
    } else {
        led_init<<<1, 64, 0, stream>>>(ws);
        led_scan<true><<<grid, 256, 0, stream>>>(X, colors, ws);
        led_final_atomic<<<1, 64, 0, stream>>>(ws, out);
    }
}